// Round 1
// baseline (363.364 us; speedup 1.0000x reference)
//
#include <hip/hip_runtime.h>
#include <cstdint>
#include <cstddef>

typedef __attribute__((ext_vector_type(8))) short bf16x8;
typedef __attribute__((ext_vector_type(4))) float f32x4;
typedef __attribute__((ext_vector_type(8))) unsigned short ushort8;

#define FIX_CAP 65536
// flag margin: proven 1e-3 (3-term bf16 error ~1e-6) + 2*2.4e-4 key-quantization slack
#define MARGIN2 1.5e-3f

__device__ __forceinline__ unsigned short f2bf(float f) {
  union { float f; unsigned int u; } x; x.f = f;
  unsigned int r = (x.u + 0x7fffu + ((x.u >> 16) & 1u)) >> 16;  // RNE
  return (unsigned short)r;
}
__device__ __forceinline__ float bf2f(unsigned short h) {
  union { unsigned int u; float f; } x; x.u = ((unsigned int)h) << 16;
  return x.f;
}
// monotone float -> sortable u32 ordinal
__device__ __forceinline__ unsigned int f2ord(float v) {
  unsigned int s = __float_as_uint(v);
  return s ^ ((unsigned int)((int)s >> 31) | 0x80000000u);
}
__device__ __forceinline__ float ord2f(unsigned int o) {
  unsigned int s = (o & 0x80000000u) ? (o ^ 0x80000000u) : ~o;
  return __uint_as_float(s);
}

// ---------------------------------------------------------------------------
// kprep: fused {zero Mt + cnt, W3->bf16, W1->hi/lo bf16, const[k]=W3[k,:]·b2+b3[k]}
// grid = 512 + 256 + 256 + 128 = 1152 blocks; bodies are independent.
// ---------------------------------------------------------------------------
__global__ __launch_bounds__(256) void kprep(
    float* __restrict__ Mt, int* __restrict__ cnt,
    const float* __restrict__ W3, unsigned short* __restrict__ W3b,
    const float* __restrict__ W1, unsigned short* __restrict__ w1h,
    unsigned short* __restrict__ w1l,
    const float* __restrict__ b2, const float* __restrict__ b3,
    float* __restrict__ constv) {
  __shared__ float red[4];
  const int bid = blockIdx.x;
  const int t = threadIdx.x;
  if (bid < 512) {
    int e = bid * 256 + t;  // 512*256 = 131072 float4 = 2 MB
    ((float4*)Mt)[e] = (float4){0.f, 0.f, 0.f, 0.f};
    if (e == 0) cnt[0] = 0;
  } else if (bid < 768) {
    int e = ((bid - 512) * 256 + t) * 8;  // W3: 128*4096 elems
    float4 f0 = *(const float4*)(W3 + e);
    float4 f1 = *(const float4*)(W3 + e + 4);
    ushort8 v;
    v[0] = f2bf(f0.x); v[1] = f2bf(f0.y); v[2] = f2bf(f0.z); v[3] = f2bf(f0.w);
    v[4] = f2bf(f1.x); v[5] = f2bf(f1.y); v[6] = f2bf(f1.z); v[7] = f2bf(f1.w);
    *(ushort8*)(W3b + e) = v;
  } else if (bid < 1024) {
    int e = ((bid - 768) * 256 + t) * 8;  // W1: 4096*128 elems
    float ff[8];
    *(float4*)&ff[0] = *(const float4*)(W1 + e);
    *(float4*)&ff[4] = *(const float4*)(W1 + e + 4);
    ushort8 h, l;
#pragma unroll
    for (int i = 0; i < 8; i++) {
      unsigned short hi = f2bf(ff[i]);
      h[i] = hi;
      l[i] = f2bf(ff[i] - bf2f(hi));
    }
    *(ushort8*)(w1h + e) = h;
    *(ushort8*)(w1l + e) = l;
  } else {
    int k = bid - 1024;  // 128 rows
    float s = 0.f;
    for (int j = t; j < 4096; j += 256) s += W3[k * 4096 + j] * b2[j];
#pragma unroll
    for (int mk = 1; mk < 64; mk <<= 1) s += __shfl_xor(s, mk, 64);
    if ((t & 63) == 0) red[t >> 6] = s;
    __syncthreads();
    if (t == 0) constv[k] = red[0] + red[1] + red[2] + red[3] + b3[k];
  }
}

// ---------------------------------------------------------------------------
// K1: o = x @ W1^T + b1 via bf16 MFMA 3-term split (xh*wh + xh*wl + xl*wh),
// fused per-segment top-2 argmax.
// NEW STRUCTURE: 1-D grid of 512 blocks; each block owns 64 rows and loops
// over ALL 16 segments, so the x hi/lo staging (VALU conversion + HBM read)
// is amortized 16x. W1 hi/lo (2 MB) streams from L2. Per-block MFMA work is
// ~16x larger -> MFMA-bound instead of epilogue-bound.
// Epilogue: ordinal-packed u32 keys ((ord & 0xFFFFFF00) | (255 - col)) so
// argmax + lowest-col tie-break is a single unsigned max; merged via a small
// LDS key buffer (phase A: per-thread top-of-4 per row-slot; phase B: 4
// threads/row scan 16 entries each + 2-step shfl top-2; phase C: winner
// entry's internal 2nd for the margin test). Near-ties (quantized gap <
// MARGIN2) are flagged for the exact fp32 fixup, a strict superset of the
// proven margin-1e-3 flag set (key truncation error <= 2.4e-4 per value).
// MFMA order is IDENTICAL to the verified kernel -> bit-identical logits.
// ---------------------------------------------------------------------------
__global__ __launch_bounds__(256, 2) void k1_mfma(
    const float* __restrict__ x, const unsigned short* __restrict__ w1h,
    const unsigned short* __restrict__ w1l, const float* __restrict__ b1,
    int* __restrict__ idxbuf, int* __restrict__ cnt, int* __restrict__ list) {
  __shared__ unsigned short xsh[64 * 136];  // stride 136 shorts: 2-way-free banks
  __shared__ unsigned short xsl[64 * 136];
  __shared__ unsigned int kbuf[64 * 68];    // [row][entry(wv*16+m)], stride 68: 2-way-free
  __shared__ unsigned int rowres[64];       // winner key per row
  __shared__ unsigned int rowres2[64];      // winner-entry internal 2nd key per row

  const int t = threadIdx.x;
  const int r0 = blockIdx.x * 64;

  // ---- stage x rows 64x128, on-the-fly hi/lo bf16 split (ONCE per block) ----
#pragma unroll
  for (int it = 0; it < 4; it++) {
    int ch = it * 256 + t;          // 1024 chunks of 8 elems
    int row = ch >> 4, k8 = ch & 15;
    float ff[8];
    *(float4*)&ff[0] = *(const float4*)(x + (r0 + row) * 128 + k8 * 8);
    *(float4*)&ff[4] = *(const float4*)(x + (r0 + row) * 128 + k8 * 8 + 4);
    ushort8 h, l;
#pragma unroll
    for (int i = 0; i < 8; i++) {
      unsigned short hi = f2bf(ff[i]);
      h[i] = hi;
      l[i] = f2bf(ff[i] - bf2f(hi));
    }
    *(ushort8*)&xsh[row * 136 + k8 * 8] = h;
    *(ushort8*)&xsl[row * 136 + k8 * 8] = l;
  }
  __syncthreads();

  const int lane = t & 63, wv = t >> 6;
  const int m = lane & 15, q = lane >> 4;
  const int browB = t >> 2, partB = t & 3;  // phase-B mapping: 4 threads per row

  for (int seg = 0; seg < 16; ++seg) {
    const int cbase = seg * 256 + wv * 64;  // global col of (nt=0, n16=0)

    f32x4 acc[4][4];
#pragma unroll
    for (int mt = 0; mt < 4; mt++)
#pragma unroll
      for (int nt = 0; nt < 4; nt++) acc[mt][nt] = (f32x4){0.f, 0.f, 0.f, 0.f};

#pragma unroll
    for (int ks = 0; ks < 4; ks++) {
      const int k0 = ks * 32;
      bf16x8 ah[4], al[4];
#pragma unroll
      for (int mt = 0; mt < 4; mt++) {
        ah[mt] = *(const bf16x8*)&xsh[(mt * 16 + m) * 136 + k0 + q * 8];
        al[mt] = *(const bf16x8*)&xsl[(mt * 16 + m) * 136 + k0 + q * 8];
      }
#pragma unroll
      for (int nt = 0; nt < 4; nt++) {
        const size_t woff = (size_t)(cbase + nt * 16 + m) * 128 + k0 + q * 8;
        bf16x8 bh = *(const bf16x8*)(w1h + woff);
        bf16x8 bl = *(const bf16x8*)(w1l + woff);
#pragma unroll
        for (int mt = 0; mt < 4; mt++) {
          acc[mt][nt] = __builtin_amdgcn_mfma_f32_16x16x32_bf16(ah[mt], bh, acc[mt][nt], 0, 0, 0);
          acc[mt][nt] = __builtin_amdgcn_mfma_f32_16x16x32_bf16(ah[mt], bl, acc[mt][nt], 0, 0, 0);
          acc[mt][nt] = __builtin_amdgcn_mfma_f32_16x16x32_bf16(al[mt], bh, acc[mt][nt], 0, 0, 0);
        }
      }
    }

    // ---- phase A: per-thread max-key over its 4 cols per row-slot ----
    float bias[4];
#pragma unroll
    for (int nt = 0; nt < 4; nt++) bias[nt] = b1[cbase + nt * 16 + m];

#pragma unroll
    for (int mt = 0; mt < 4; mt++)
#pragma unroll
      for (int reg = 0; reg < 4; reg++) {
        unsigned int kk = 0u;
#pragma unroll
        for (int nt = 0; nt < 4; nt++) {
          float v = acc[mt][nt][reg] + bias[nt];
          unsigned int col = (unsigned)(wv * 64 + nt * 16 + m);
          unsigned int key = (f2ord(v) & 0xFFFFFF00u) | (255u - col);
          kk = kk > key ? kk : key;
        }
        kbuf[(mt * 16 + q * 4 + reg) * 68 + wv * 16 + m] = kk;
      }
    __syncthreads();

    // ---- phase B: 4 threads per row scan 16 entries each, top-2 of entry-tops ----
    unsigned int K1 = 0u, K2 = 0u;
    {
      const uint4* kp = (const uint4*)&kbuf[browB * 68 + partB * 16];
#pragma unroll
      for (int i = 0; i < 4; i++) {
        uint4 u = kp[i];
        unsigned int kv0 = u.x, kv1 = u.y, kv2 = u.z, kv3 = u.w;
        unsigned int hi, lo;
        hi = K1 > kv0 ? K1 : kv0; lo = K1 > kv0 ? kv0 : K1; K1 = hi; K2 = K2 > lo ? K2 : lo;
        hi = K1 > kv1 ? K1 : kv1; lo = K1 > kv1 ? kv1 : K1; K1 = hi; K2 = K2 > lo ? K2 : lo;
        hi = K1 > kv2 ? K1 : kv2; lo = K1 > kv2 ? kv2 : K1; K1 = hi; K2 = K2 > lo ? K2 : lo;
        hi = K1 > kv3 ? K1 : kv3; lo = K1 > kv3 ? kv3 : K1; K1 = hi; K2 = K2 > lo ? K2 : lo;
      }
#pragma unroll
      for (int msk = 1; msk <= 2; msk <<= 1) {
        unsigned int o1 = (unsigned int)__shfl_xor((int)K1, msk, 64);
        unsigned int o2 = (unsigned int)__shfl_xor((int)K2, msk, 64);
        unsigned int hi = K1 > o1 ? K1 : o1;
        unsigned int lo = K1 > o1 ? o1 : K1;
        unsigned int m2 = K2 > o2 ? K2 : o2;
        K1 = hi; K2 = m2 > lo ? m2 : lo;
      }
      if (partB == 0) rowres[browB] = K1;
    }
    __syncthreads();

    // ---- phase C: winner-entry owner recomputes its internal 2nd (exact v2) ----
#pragma unroll
    for (int mt = 0; mt < 4; mt++)
#pragma unroll
      for (int reg = 0; reg < 4; reg++) {
        int row = mt * 16 + q * 4 + reg;
        unsigned int kk1 = rowres[row];  // LDS broadcast across m-lanes
        int colw = 255 - (int)(kk1 & 255u);
        if ((colw >> 6) == wv && (colw & 15) == m) {
          int nt1 = (colw >> 4) & 3;
          unsigned int k2i = 0u;
#pragma unroll
          for (int nt = 0; nt < 4; nt++) {
            if (nt == nt1) continue;
            float v = acc[mt][nt][reg] + bias[nt];
            unsigned int col = (unsigned)(wv * 64 + nt * 16 + m);
            unsigned int key = (f2ord(v) & 0xFFFFFF00u) | (255u - col);
            k2i = k2i > key ? k2i : key;
          }
          rowres2[row] = k2i;
        }
      }
    __syncthreads();

    // ---- final: leader per row emits idx + near-tie flag ----
    if (partB == 0) {
      unsigned int k2f = rowres2[browB];
      k2f = k2f > K2 ? k2f : K2;
      int colw = 255 - (int)(K1 & 255u);
      int b = r0 + browB;
      idxbuf[b * 16 + seg] = colw;
      float v1 = ord2f(K1 & 0xFFFFFF00u);
      float v2 = ord2f(k2f & 0xFFFFFF00u);
      if (v1 - v2 < MARGIN2) {
        int p = atomicAdd(cnt, 1);
        if (p < FIX_CAP) list[p] = (b << 4) | seg;
      }
    }
    // no extra barrier: >=2 barriers separate this seg's kbuf/rowres/rowres2
    // readers from the next seg's writers.
  }
}

// ---------------------------------------------------------------------------
// K1fix: for flagged (b,seg), recompute all 256 logits in EXACT baseline fp32
// order (acc = b1[c]; ascending-k fmaf) — one column per thread — and take
// the argmax with lowest-index tie-break. Unchanged proven numerics; grid is
// now 1024 blocks (gridDim-stride) for latency.
// ---------------------------------------------------------------------------
__global__ __launch_bounds__(256) void k1_fix(
    const float* __restrict__ x, const float* __restrict__ W1,
    const float* __restrict__ b1, const int* __restrict__ cnt,
    const int* __restrict__ list, int* __restrict__ idxbuf) {
  __shared__ float redv[4];
  __shared__ int   redi[4];
  const int t = threadIdx.x;
  const int lane = t & 63, wv = t >> 6;
  int n = cnt[0]; if (n > FIX_CAP) n = FIX_CAP;
  for (int e = blockIdx.x; e < n; e += gridDim.x) {
    int pk = list[e];
    int b = pk >> 4, seg = pk & 15;
    int c = seg * 256 + t;
    float a = b1[c];
    const float4* xr = (const float4*)(x + b * 128);   // broadcast reads
    const float4* wr = (const float4*)(W1 + (size_t)c * 128);
#pragma unroll 8
    for (int k4 = 0; k4 < 32; k4++) {
      float4 xv = xr[k4];
      float4 wv4 = wr[k4];
      a = fmaf(xv.x, wv4.x, a);
      a = fmaf(xv.y, wv4.y, a);
      a = fmaf(xv.z, wv4.z, a);
      a = fmaf(xv.w, wv4.w, a);
    }
    // argmax over 256 threads, lowest-index tie-break
    float v = a; int li = t;
#pragma unroll
    for (int msk = 1; msk < 64; msk <<= 1) {
      float u = __shfl_xor(v, msk, 64);
      int ju = __shfl_xor(li, msk, 64);
      if (u > v || (u == v && ju < li)) { v = u; li = ju; }
    }
    if (lane == 0) { redv[wv] = v; redi[wv] = li; }
    __syncthreads();
    if (t == 0) {
      float bv = redv[0]; int bi = redi[0];
#pragma unroll
      for (int w = 1; w < 4; w++) {
        if (redv[w] > bv || (redv[w] == bv && redi[w] < bi)) { bv = redv[w]; bi = redi[w]; }
      }
      idxbuf[b * 16 + seg] = bi;
    }
    __syncthreads();
  }
}

// ---------------------------------------------------------------------------
// K2: Mt[c,k] += sum_{j in chunk} W2[j,c]*W3[k,j] via bf16 MFMA, split-K=8,
// 4 waves/block, atomic f32 accumulate into zeroed Mt (order jitter ~1e-7).
// ---------------------------------------------------------------------------
__global__ __launch_bounds__(256) void k2_mfma(const float* __restrict__ W2,
                                               const unsigned short* __restrict__ W3b,
                                               float* __restrict__ Mt) {
  const int t = threadIdx.x;
  const int lane = t & 63, wv = t >> 6;
  const int c0 = (blockIdx.x * 4 + wv) * 16;  // 64 blocks * 4 waves -> 4096 c
  const int jq = blockIdx.y;                  // 8 K-chunks of 512
  const int m = lane & 15, q = lane >> 4;
  f32x4 acc[8];
#pragma unroll
  for (int nt = 0; nt < 8; nt++) acc[nt] = (f32x4){0.f, 0.f, 0.f, 0.f};

  for (int it = 0; it < 16; it++) {
    const int j0 = jq * 512 + it * 32;
    union { bf16x8 v; unsigned short u[8]; } a;
    const float* ap = W2 + (size_t)(j0 + q * 8) * 4096 + c0 + m;
#pragma unroll
    for (int i = 0; i < 8; i++) a.u[i] = f2bf(ap[(size_t)i * 4096]);
#pragma unroll
    for (int nt = 0; nt < 8; nt++) {
      bf16x8 b = *(const bf16x8*)(W3b + (nt * 16 + m) * 4096 + j0 + q * 8);
      acc[nt] = __builtin_amdgcn_mfma_f32_16x16x32_bf16(a.v, b, acc[nt], 0, 0, 0);
    }
  }
#pragma unroll
  for (int nt = 0; nt < 8; nt++)
#pragma unroll
    for (int r = 0; r < 4; r++)
      atomicAdd(&Mt[(size_t)(c0 + q * 4 + r) * 128 + nt * 16 + m], acc[nt][r]);
}

// ---------------------------------------------------------------------------
// K3: out[b,k] = const[k] + sum_g Mt[g*256 + idx[b,g], k]
// ---------------------------------------------------------------------------
__global__ __launch_bounds__(256) void k3_gather(const int* __restrict__ idxbuf,
                                                 const float* __restrict__ Mt,
                                                 const float* __restrict__ constv,
                                                 float* __restrict__ out) {
  const int t = threadIdx.x;
  const int w = t >> 6;
  const int lane = t & 63;
  const int b = blockIdx.x * 4 + w;
  float a0 = constv[lane];
  float a1 = constv[lane + 64];
  const int* ib = idxbuf + b * 16;
  int cg[16];
#pragma unroll
  for (int g = 0; g < 16; g++) cg[g] = g * 256 + ib[g];
#pragma unroll
  for (int g = 0; g < 16; g++) {
    const float* mrow = Mt + (size_t)cg[g] * 128;
    a0 += mrow[lane];
    a1 += mrow[lane + 64];
  }
  out[b * 128 + lane] = a0;
  out[b * 128 + lane + 64] = a1;
}

// ---------------------------------------------------------------------------
extern "C" void kernel_launch(void* const* d_in, const int* in_sizes, int n_in,
                              void* d_out, int out_size, void* d_ws, size_t ws_size,
                              hipStream_t stream) {
  const float* x  = (const float*)d_in[0];   // [32768,128]
  const float* W1 = (const float*)d_in[1];   // [4096,128]
  const float* b1 = (const float*)d_in[2];   // [4096]
  const float* W2 = (const float*)d_in[3];   // [4096,4096]
  const float* b2 = (const float*)d_in[4];   // [4096]
  const float* W3 = (const float*)d_in[5];   // [128,4096]
  const float* b3 = (const float*)d_in[6];   // [128]
  float* out = (float*)d_out;                // [32768,128]

  // workspace layout (~7.3 MB, all regions rewritten every call)
  char* w = (char*)d_ws;
  int* idxbuf         = (int*)(w);                           // 2 MB  [32768,16]
  unsigned short* W3b = (unsigned short*)(w + (2u << 20));   // 1 MB  [128,4096] bf16
  float* Mt           = (float*)(w + (3u << 20));            // 2 MB  [4096,128] f32
  unsigned short* w1h = (unsigned short*)(w + (5u << 20));   // 1 MB  [4096,128] bf16 hi
  unsigned short* w1l = (unsigned short*)(w + (6u << 20));   // 1 MB  [4096,128] bf16 lo
  float* constv       = (float*)(w + (7u << 20));            // 512 B [128]
  int* cnt            = (int*)(w + (7u << 20) + 1024);       // 4 B
  int* fixlist        = (int*)(w + (7u << 20) + 4096);       // 256 KB

  kprep<<<1152, 256, 0, stream>>>(Mt, cnt, W3, W3b, W1, w1h, w1l, b2, b3, constv);
  k1_mfma<<<512, 256, 0, stream>>>(x, w1h, w1l, b1, idxbuf, cnt, fixlist);
  k1_fix<<<1024, 256, 0, stream>>>(x, W1, b1, cnt, fixlist, idxbuf);
  k2_mfma<<<dim3(64, 8), 256, 0, stream>>>(W2, W3b, Mt);
  k3_gather<<<8192, 256, 0, stream>>>(idxbuf, Mt, constv, out);
}